// Round 5
// baseline (186.137 us; speedup 1.0000x reference)
//
#include <hip/hip_runtime.h>
#include <cstddef>

// QSelfAttention MI355X round 13: TRUE counted-vmcnt pipeline (T4).
// Post-mortem r12: my "dbuf" still drained vmcnt(0) inside every step
// (__syncthreads in gemm_core; step-6 drain in flash) -> prefetch never
// survived a barrier; r8 (4 blk/CU, drain) == r12 (2 blk/CU, fake dbuf).
// This round, both flash chunks and gemm k-steps use:
//   issue(next,N loads) -> vmcnt(N) [vmcnt(0) only on last] -> SB(0) ->
//   s_barrier(B) -> compute -> lgkmcnt(0) -> SB(0) -> s_barrier(A)
// Steady state has ZERO vm drains: data waited on was issued a full step
// ago. WAR: reads lgkm-drained before barrier A, overwrite issued after.
// RAW: vmcnt(N) retires everything older than the N just-issued.
// sched_barrier(0) after each asm wait (rule #18: MFMA hoists past asm).

typedef unsigned short ushort_t;
typedef __attribute__((ext_vector_type(8))) short bf16x8;
typedef __attribute__((ext_vector_type(4))) float f32x4;
typedef __attribute__((ext_vector_type(2))) float f32x2;
typedef __attribute__((ext_vector_type(2))) unsigned u32x2;

#define QSCALE 0.18033688011112042f  // 0.125 * log2(e)

__device__ __forceinline__ ushort_t f2bf_t(float f) {
  return (ushort_t)(__float_as_uint(f) >> 16);
}
__device__ __forceinline__ unsigned pk2bf(float lo, float hi) {
  return __builtin_amdgcn_perm(__float_as_uint(hi), __float_as_uint(lo),
                               0x07060302u);
}

__device__ __forceinline__ void gload16(const ushort_t* g, ushort_t* l) {
  __builtin_amdgcn_global_load_lds(
      (const __attribute__((address_space(1))) void*)g,
      (__attribute__((address_space(3))) void*)l, 16, 0, 0);
}

// ---------------------------------------------------------------------------
// Core NT GEMM: D[M][N] = A[M][K] * B[N][K]^T, bf16 in, fp32 acc.
// TM in {64,128}, TN=128, BK=64, 256 threads (4 waves, 2x2 wave grid).
// Counted-vmcnt double-buffered pipeline (see header). NLD = TM/32 + 4
// loads per thread per k-step (A: TM/32, B: 4).
template <int TM>
__device__ __forceinline__ void gemm_core(
    const ushort_t* __restrict__ A, int lda,
    const ushort_t* __restrict__ B, int ldb,
    int K, int m0, int n0,
    ushort_t* As, ushort_t* Bs, f32x4 (*acc)[4])
{
  constexpr int MT  = TM / 32;
  constexpr int WTM = TM / 2;
  const int t = threadIdx.x;
  const int lane = t & 63, quad = lane >> 4, l15 = lane & 15;
  const int w = t >> 6, wm = w >> 1, wn = w & 1;
  const int rr = (lane >> 3) & 7;
  const int gg = (lane & 7) ^ rr;

  auto stage = [&](int k0, int pbuf) {
    ushort_t* Ad = As + pbuf * (TM * 64);
    ushort_t* Bd = Bs + pbuf * (128 * 64);
    #pragma unroll
    for (int i = 0; i < TM / 32; ++i) {
      const int mrow = w * (TM / 4) + i * 8;
      gload16(A + (size_t)(m0 + mrow + rr) * lda + k0 + gg * 8, Ad + mrow * 64);
    }
    #pragma unroll
    for (int i = 0; i < 4; ++i) {
      const int mrow = w * 32 + i * 8;
      gload16(B + (size_t)(n0 + mrow + rr) * ldb + k0 + gg * 8, Bd + mrow * 64);
    }
  };

  stage(0, 0);  // in flight; waited via first iteration's vmcnt(NLD)

  #pragma unroll
  for (int i = 0; i < MT; ++i)
    #pragma unroll
    for (int j = 0; j < 4; ++j) acc[i][j] = (f32x4){0.f, 0.f, 0.f, 0.f};

  int pb = 0;
  for (int k0 = 0; k0 < K; k0 += 64) {
    // 1) prefetch next k-tile, then counted wait: current tile landed.
    if (k0 + 64 < K) {
      stage(k0 + 64, pb ^ 1);
      if constexpr (TM == 128)
        asm volatile("s_waitcnt vmcnt(8)" ::: "memory");
      else
        asm volatile("s_waitcnt vmcnt(6)" ::: "memory");
    } else {
      asm volatile("s_waitcnt vmcnt(0)" ::: "memory");
    }
    __builtin_amdgcn_sched_barrier(0);
    __builtin_amdgcn_s_barrier();  // B: buf[pb] visible to all waves

    const ushort_t* Ac = As + pb * (TM * 64);
    const ushort_t* Bc = Bs + pb * (128 * 64);
    #pragma unroll
    for (int kk = 0; kk < 2; ++kk) {
      const int gq = kk * 4 + quad;
      const int sg = (gq ^ (l15 & 7)) * 8;
      bf16x8 af[MT], bfr[4];
      #pragma unroll
      for (int i = 0; i < MT; ++i)
        af[i] = *(const bf16x8*)(Ac + (wm * WTM + i * 16 + l15) * 64 + sg);
      #pragma unroll
      for (int j = 0; j < 4; ++j)
        bfr[j] = *(const bf16x8*)(Bc + (wn * 64 + j * 16 + l15) * 64 + sg);
      #pragma unroll
      for (int i = 0; i < MT; ++i)
        #pragma unroll
        for (int j = 0; j < 4; ++j)
          acc[i][j] = __builtin_amdgcn_mfma_f32_16x16x32_bf16(
              af[i], bfr[j], acc[i][j], 0, 0, 0);
    }
    // 2) own ds_reads of buf[pb] retired -> barrier A: next step may
    //    overwrite buf[pb] (its DMA is issued only after this barrier).
    asm volatile("s_waitcnt lgkmcnt(0)" ::: "memory");
    __builtin_amdgcn_sched_barrier(0);
    __builtin_amdgcn_s_barrier();  // A
    pb ^= 1;
  }
}

template <int TM, class F>
__device__ __forceinline__ void store_bf16(
    ushort_t* lds, ushort_t* __restrict__ out, int ldo, int m0, int n0,
    f32x4 (*acc)[4], F f)
{
  constexpr int MT = TM / 32, WTM = TM / 2, SI = TM / 16;
  const int t = threadIdx.x;
  const int lane = t & 63, quad = lane >> 4, l15 = lane & 15;
  const int w = t >> 6, wm = w >> 1, wn = w & 1;
  #pragma unroll
  for (int i = 0; i < MT; ++i)
    #pragma unroll
    for (int j = 0; j < 4; ++j)
      #pragma unroll
      for (int r = 0; r < 4; ++r) {
        const int rl = wm * WTM + i * 16 + quad * 4 + r;
        const int cl = wn * 64 + j * 16 + l15;
        lds[rl * 136 + cl] = f2bf_t(f(i, j, r, rl, cl, acc[i][j][r]));
      }
  __syncthreads();
  #pragma unroll
  for (int i = 0; i < SI; ++i) {
    const int s = i * 256 + t, m = s >> 4, g = s & 15;
    const uint4 v = *(const uint4*)(lds + m * 136 + g * 8);
    *(uint4*)(out + (size_t)(m0 + m) * ldo + n0 + g * 8) = v;
  }
}

// ---------------------------------------------------------------------------
// prep: x[b][c][n] fp32 -> xbfT[b][n][c] bf16 (64x64 tiles, blockIdx.y<8)
//       + all weight fp32->bf16 conversions (blockIdx.y==8)
__global__ __launch_bounds__(256) void prep_x(
    const float* __restrict__ x,
    const float* __restrict__ Wq, const float* __restrict__ Wk,
    const float* __restrict__ Wv, const float* __restrict__ Wo,
    ushort_t* __restrict__ xbfT, ushort_t* __restrict__ Wqk,
    ushort_t* __restrict__ Wvb, ushort_t* __restrict__ Wob)
{
  __shared__ float T[64 * 66];
  const int t = threadIdx.x;
  if (blockIdx.y == 8) {
    const int id = blockIdx.z * 16 + blockIdx.x;
    #pragma unroll
    for (int p = 0; p < 5; ++p) {
      const int s = p * 256 + t;
      if (s < 1152) {
        const int u = id * 1152 + s;
        const int e = u * 2;
        float f0, f1;
        if (e < 32768)       { f0 = Wq[e];         f1 = Wq[e + 1]; }
        else if (e < 65536)  { f0 = Wk[e - 32768]; f1 = Wk[e - 32767]; }
        else if (e < 327680) { f0 = Wv[e - 65536]; f1 = Wv[e - 65535]; }
        else                 { f0 = Wo[e - 327680]; f1 = Wo[e - 327679]; }
        const unsigned pk = pk2bf(f0, f1);
        if (e < 65536)       *((unsigned*)Wqk + u) = pk;
        else if (e < 327680) *((unsigned*)Wvb + (u - 32768)) = pk;
        else                 *((unsigned*)Wob + (u - 163840)) = pk;
      }
    }
    return;
  }
  const int b = blockIdx.z, c0 = blockIdx.y * 64, n0 = blockIdx.x * 64;
  const float* xb = x + ((size_t)b * 512 + c0) * 1024 + n0;
  const int njf = t & 15, ci0 = t >> 4;
  #pragma unroll
  for (int p = 0; p < 4; ++p) {
    const int ci = p * 16 + ci0;
    const f32x4 v = *(const f32x4*)(xb + (size_t)ci * 1024 + njf * 4);
    float* d = &T[ci * 66 + njf * 4];
    *(f32x2*)(d)     = (f32x2){v[0], v[1]};
    *(f32x2*)(d + 2) = (f32x2){v[2], v[3]};
  }
  __syncthreads();
  const int c4 = (t & 15) * 4, nr0 = t >> 4;
  #pragma unroll
  for (int p = 0; p < 4; ++p) {
    const int nr = p * 16 + nr0;
    const float a0 = T[(c4 + 0) * 66 + nr];
    const float a1 = T[(c4 + 1) * 66 + nr];
    const float a2 = T[(c4 + 2) * 66 + nr];
    const float a3 = T[(c4 + 3) * 66 + nr];
    const u32x2 pkv = {pk2bf(a0, a1), pk2bf(a2, a3)};
    *(u32x2*)&xbfT[((size_t)b * 1024 + n0 + nr) * 512 + c0 + c4] = pkv;
  }
}

// ---------------------------------------------------------------------------
// k1 fused, batch-contiguous work ids + bijective XCD swizzle (768 = 8*96)
__global__ __launch_bounds__(256) void k1_fused(
    const ushort_t* __restrict__ xbfT, const ushort_t* __restrict__ Wqk,
    const ushort_t* __restrict__ Wvb,
    const float* __restrict__ bq, const float* __restrict__ bk,
    const float* __restrict__ bv,
    ushort_t* __restrict__ qkt, ushort_t* __restrict__ vt2)
{
  __shared__ __align__(16) ushort_t lds[32768];  // 64KB: dbuf staging
  const unsigned lin = blockIdx.x;
  const unsigned wid = (lin & 7) * 96 + (lin >> 3);
  const int b = wid / 48, r = wid % 48;
  const int t = threadIdx.x, lane = t & 63, quad = lane >> 4, l15 = lane & 15;
  const int w = t >> 6, wm = w >> 1, wn = w & 1;
  if (r < 32) {
    const int m0 = (r >> 3) * 128, n0 = (r & 7) * 128;
    f32x4 acc[4][4];
    gemm_core<128>(Wvb, 512, xbfT + (size_t)b * 524288, 512, 512, m0, n0,
                   lds, lds + 16384, acc);
    float br[4][4];
    #pragma unroll
    for (int i = 0; i < 4; ++i)
      #pragma unroll
      for (int rr2 = 0; rr2 < 4; ++rr2)
        br[i][rr2] = bv[m0 + wm * 64 + i * 16 + quad * 4 + rr2];
    store_bf16<128>(lds, vt2 + (size_t)b * 524288, 1024, m0, n0, acc,
        [&](int i, int, int rr2, int, int, float v) { return v + br[i][rr2]; });
  } else {
    const int m0 = (r - 32) * 64;
    f32x4 acc[2][4];
    gemm_core<64>(xbfT + (size_t)b * 524288, 512, Wqk, 512, 512, m0, 0,
                  lds, lds + 8192, acc);
    float bc[4], qs[4];
    #pragma unroll
    for (int j = 0; j < 4; ++j) {
      const int col = wn * 64 + j * 16 + l15;
      bc[j] = (col < 64) ? bq[col] : bk[col - 64];
      qs[j] = (col < 64) ? QSCALE : 1.0f;
    }
    store_bf16<64>(lds, qkt + (size_t)b * 131072, 128, m0, 0, acc,
        [&](int, int j, int, int, int, float v) { return (v + bc[j]) * qs[j]; });
  }
}

// ---------------------------------------------------------------------------
// flash: per block (b, 64 q-rows m0, 128 c-cols c0); 16 chunks of 64 keys.
// Counted-vmcnt pipeline, 3 barriers/chunk, zero vm drains in steady state:
//   issue(next,6) -> vmcnt(6) -> bar B -> S -> exp2 -> lgkm(0) -> bar C ->
//   PV -> lgkm(0) -> bar A
__global__ __launch_bounds__(256) void flash_attn(
    const ushort_t* __restrict__ qkt, const ushort_t* __restrict__ vt2,
    ushort_t* __restrict__ o1)
{
  __shared__ __align__(16) ushort_t buf[33792];
  __shared__ float lsum[64][2];
  ushort_t* Ks0 = buf;            // 2 x 4096 ush
  ushort_t* Vs0 = buf + 8192;     // 2 x 8192 ush
  ushort_t* Ps0 = buf + 24576;    // 2 x 4608 ush (stride 72); Q-stage uses Ps0

  const int t = threadIdx.x;
  const int lane = t & 63, quad = lane >> 4, l15 = lane & 15;
  const int w = t >> 6, wm = w >> 1, wn = w & 1;
  const int rr = (lane >> 3) & 7, gg = (lane & 7) ^ rr;

  const unsigned lin = blockIdx.x;
  const unsigned wid = (lin & 7) * 128 + (lin >> 3);
  const int b  = wid >> 6;
  const int m0 = ((wid >> 2) & 15) * 64;
  const int c0 = (wid & 3) * 128;

  const ushort_t* qb = qkt + (size_t)b * 131072;   // [n][128]: q 0..63, k 64..127
  const ushort_t* vb = vt2 + (size_t)b * 524288;   // [c][1024]

  // ---- prologue: stage Q (64x64) into Ps0 region
  #pragma unroll
  for (int i = 0; i < 2; ++i) {
    const int mrow = w * 16 + i * 8;
    gload16(qb + (size_t)(m0 + mrow + rr) * 128 + gg * 8, Ps0 + mrow * 64);
  }
  asm volatile("s_waitcnt vmcnt(0)" ::: "memory");
  __builtin_amdgcn_sched_barrier(0);
  __builtin_amdgcn_s_barrier();

  bf16x8 af_q[2][2];
  #pragma unroll
  for (int kk = 0; kk < 2; ++kk) {
    const int sg = ((kk * 4 + quad) ^ (l15 & 7)) * 8;
    #pragma unroll
    for (int i = 0; i < 2; ++i)
      af_q[i][kk] = *(const bf16x8*)(Ps0 + (wm * 32 + i * 16 + l15) * 64 + sg);
  }

  const ushort_t* kp = qb + (size_t)(w * 16 + rr) * 128 + 64 + gg * 8;
  const ushort_t* vp = vb + (size_t)(c0 + w * 32 + rr) * 1024 + gg * 8;

  // stage chunk 0 into buf0; drain everything (incl. Q-frag ds_reads) once.
  #pragma unroll
  for (int i = 0; i < 2; ++i)
    gload16(kp + i * 1024, Ks0 + (w * 16 + i * 8) * 64);
  #pragma unroll
  for (int i = 0; i < 4; ++i)
    gload16(vp + i * 8192, Vs0 + (w * 32 + i * 8) * 64);
  asm volatile("s_waitcnt vmcnt(0) lgkmcnt(0)" ::: "memory");
  __builtin_amdgcn_sched_barrier(0);
  __builtin_amdgcn_s_barrier();

  f32x4 accO[2][4];
  #pragma unroll
  for (int i = 0; i < 2; ++i)
    #pragma unroll
    for (int j = 0; j < 4; ++j) accO[i][j] = (f32x4){0.f, 0.f, 0.f, 0.f};
  float rsum[2][4] = {{0.f, 0.f, 0.f, 0.f}, {0.f, 0.f, 0.f, 0.f}};

  const int psw_off = (wm * 32 + quad * 4) * 72 + wn * 32 + l15;
  const int sg0 = (quad ^ (l15 & 7)) * 8;
  const int sg1 = ((4 + quad) ^ (l15 & 7)) * 8;

  const ushort_t* kpn = kp + 8192;  // next-chunk K source
  const ushort_t* vpn = vp + 64;    // next-chunk V source
  int p = 0;

  #pragma unroll 1
  for (int mc = 0; mc < 1024; mc += 64) {
    ushort_t* Ksd = p ? Ks0 + 4096 : Ks0;
    ushort_t* Vsd = p ? Vs0 + 8192 : Vs0;
    ushort_t* Psd = p ? Ps0 + 4608 : Ps0;
    ushort_t* Ksn = p ? Ks0 : Ks0 + 4096;
    ushort_t* Vsn = p ? Vs0 : Vs0 + 8192;

    // 1) prefetch next chunk; counted wait: THIS chunk's data (issued a
    //    full chunk ago) retired; the 6 just-issued stay in flight.
    if (mc < 960) {
      #pragma unroll
      for (int i = 0; i < 2; ++i)
        gload16(kpn + i * 1024, Ksn + (w * 16 + i * 8) * 64);
      #pragma unroll
      for (int i = 0; i < 4; ++i)
        gload16(vpn + i * 8192, Vsn + (w * 32 + i * 8) * 64);
      asm volatile("s_waitcnt vmcnt(6)" ::: "memory");
    } else {
      asm volatile("s_waitcnt vmcnt(0)" ::: "memory");
    }
    __builtin_amdgcn_sched_barrier(0);
    __builtin_amdgcn_s_barrier();  // B: buf[p] visible to all waves

    // 2) S-phase: rows wm*32+{0,16}, keys wn*32+{0,16}, K=64 (Q pre-scaled)
    f32x4 accS[2][2];
    #pragma unroll
    for (int i = 0; i < 2; ++i)
      #pragma unroll
      for (int j = 0; j < 2; ++j) accS[i][j] = (f32x4){0.f, 0.f, 0.f, 0.f};
    #pragma unroll
    for (int kk = 0; kk < 2; ++kk) {
      const int sg = kk ? sg1 : sg0;
      bf16x8 bk_[2];
      #pragma unroll
      for (int j = 0; j < 2; ++j)
        bk_[j] = *(const bf16x8*)(Ksd + (wn * 32 + j * 16 + l15) * 64 + sg);
      #pragma unroll
      for (int i = 0; i < 2; ++i)
        #pragma unroll
        for (int j = 0; j < 2; ++j)
          accS[i][j] = __builtin_amdgcn_mfma_f32_16x16x32_bf16(
              af_q[i][kk], bk_[j], accS[i][j], 0, 0, 0);
    }

    // 3) exp2 -> rsum partials -> Ps[p] (trunc bf16)
    ushort_t* psw = Psd + psw_off;
    #pragma unroll
    for (int i = 0; i < 2; ++i)
      #pragma unroll
      for (int j = 0; j < 2; ++j)
        #pragma unroll
        for (int r2 = 0; r2 < 4; ++r2) {
          const float e = __builtin_amdgcn_exp2f(accS[i][j][r2]);
          rsum[i][r2] += e;
          psw[(i * 16 + r2) * 72 + j * 16] = f2bf_t(e);
        }

    // 4) S reads + Ps writes retired -> barrier C: Ps[p] visible
    asm volatile("s_waitcnt lgkmcnt(0)" ::: "memory");
    __builtin_amdgcn_sched_barrier(0);
    __builtin_amdgcn_s_barrier();  // C

    // 5) PV-phase: O[64][128] += Ps[p][64][64] . Vs[p][128][64]^T
    #pragma unroll
    for (int kk = 0; kk < 2; ++kk) {
      const int gq = kk * 4 + quad;
      const int sgv = kk ? sg1 : sg0;
      bf16x8 ap[2], bv_[4];
      #pragma unroll
      for (int i = 0; i < 2; ++i)
        ap[i] = *(const bf16x8*)(Psd + (wm * 32 + i * 16 + l15) * 72 + gq * 8);
      #pragma unroll
      for (int j = 0; j < 4; ++j)
        bv_[j] = *(const bf16x8*)(Vsd + (wn * 64 + j * 16 + l15) * 64 + sgv);
      #pragma unroll
      for (int i = 0; i < 2; ++i)
        #pragma unroll
        for (int j = 0; j < 4; ++j)
          accO[i][j] = __builtin_amdgcn_mfma_f32_16x16x32_bf16(
              ap[i], bv_[j], accO[i][j], 0, 0, 0);
    }

    // 6) PV ds_reads retired -> barrier A: next chunk may overwrite buf[p]
    //    (its DMA is issued only after this barrier). No vm drain here.
    asm volatile("s_waitcnt lgkmcnt(0)" ::: "memory");
    __builtin_amdgcn_sched_barrier(0);
    __builtin_amdgcn_s_barrier();  // A

    kpn += 8192;
    vpn += 64;
    p ^= 1;
  }

  // finish row sums: reduce over the 16 key-lanes, combine the two wn waves
  #pragma unroll
  for (int i = 0; i < 2; ++i)
    #pragma unroll
    for (int r2 = 0; r2 < 4; ++r2) {
      float s = rsum[i][r2];
      #pragma unroll
      for (int d = 1; d < 16; d <<= 1) s += __shfl_xor(s, d, 16);
      if (l15 == 0) lsum[wm * 32 + i * 16 + quad * 4 + r2][wn] = s;
    }
  __syncthreads();  // last PV's reads done; loop exited with vmcnt=0

  ushort_t* fl_b = buf;  // [64][136] = 8704 ush, fits (Ks/Vs/Ps dead)
  #pragma unroll
  for (int i = 0; i < 2; ++i)
    #pragma unroll
    for (int r2 = 0; r2 < 4; ++r2) {
      const int row = wm * 32 + i * 16 + quad * 4 + r2;
      const float inv = 1.0f / (lsum[row][0] + lsum[row][1]);
      #pragma unroll
      for (int j = 0; j < 4; ++j)
        fl_b[row * 136 + wn * 64 + j * 16 + l15] = f2bf_t(accO[i][j][r2] * inv);
    }
  __syncthreads();
  #pragma unroll
  for (int pp = 0; pp < 4; ++pp) {
    const int s = pp * 256 + t, m = s >> 4, g = s & 15;
    const uint4 v = *(const uint4*)(fl_b + m * 136 + g * 8);
    *(uint4*)(o1 + ((size_t)b * 1024 + m0 + m) * 512 + c0 + g * 8) = v;
  }
}

// ---------------------------------------------------------------------------
// K4: out[b][c][n] = g*(Wo @ o1^T + bo) + x.  M=c(512) N=n(1024) K=v(512)
__global__ __launch_bounds__(256) void k4_proj(
    const ushort_t* __restrict__ Wob, const ushort_t* __restrict__ o1,
    const float* __restrict__ bo, const float* __restrict__ gamma,
    const float* __restrict__ x, float* __restrict__ out)
{
  __shared__ __align__(16) ushort_t lds[32768];  // 64KB: dbuf staging
  const unsigned lin = blockIdx.x;
  const unsigned wid = (lin & 7) * 64 + (lin >> 3);
  const int b = wid >> 5, rem = wid & 31;
  const int m0 = (rem >> 3) * 128, n0 = (rem & 7) * 128;
  f32x4 acc[4][4];
  gemm_core<128>(Wob, 512, o1 + (size_t)b * 524288, 512, 512, m0, n0,
                 lds, lds + 16384, acc);
  const int t = threadIdx.x, lane = t & 63, quad = lane >> 4, l15 = lane & 15;
  const int w = t >> 6, wm = w >> 1, wn = w & 1;
  const float g = gamma[0];
  float br[4][4];
  #pragma unroll
  for (int i = 0; i < 4; ++i)
    #pragma unroll
    for (int r2 = 0; r2 < 4; ++r2)
      br[i][r2] = bo[m0 + wm * 64 + i * 16 + quad * 4 + r2];
  float* fl = (float*)lds;  // 64 rows x 132 f stride
  #pragma unroll
  for (int h = 0; h < 2; ++h) {
    if (wm == h) {
      #pragma unroll
      for (int i = 0; i < 4; ++i)
        #pragma unroll
        for (int j = 0; j < 4; ++j)
          #pragma unroll
          for (int r2 = 0; r2 < 4; ++r2)
            fl[(i * 16 + quad * 4 + r2) * 132 + wn * 64 + j * 16 + l15] =
                g * (acc[i][j][r2] + br[i][r2]);
    }
    __syncthreads();
    #pragma unroll
    for (int i2 = 0; i2 < 8; ++i2) {
      const int s = i2 * 256 + t, m = s >> 5, c4 = s & 31;
      f32x4 v = *(const f32x4*)(fl + m * 132 + c4 * 4);
      const size_t gi = ((size_t)b * 512 + m0 + h * 64 + m) * 1024 + n0 + c4 * 4;
      const f32x4 xr = *(const f32x4*)(x + gi);
      v += xr;
      *(f32x4*)(out + gi) = v;
    }
    __syncthreads();
  }
}

// ---------------------------------------------------------------------------
extern "C" void kernel_launch(void* const* d_in, const int* in_sizes, int n_in,
                              void* d_out, int out_size, void* d_ws, size_t ws_size,
                              hipStream_t stream) {
  const float* x     = (const float*)d_in[0];
  const float* Wq    = (const float*)d_in[1];
  const float* bq    = (const float*)d_in[2];
  const float* Wk    = (const float*)d_in[3];
  const float* bk    = (const float*)d_in[4];
  const float* Wv    = (const float*)d_in[5];
  const float* bv    = (const float*)d_in[6];
  const float* Wo    = (const float*)d_in[7];
  const float* bo    = (const float*)d_in[8];
  const float* gamma = (const float*)d_in[9];
  float* out = (float*)d_out;

  char* wsp = (char*)d_ws;
  ushort_t* xbfT   = (ushort_t*)wsp;  wsp += (size_t)16 * 1024 * 512 * 2;  // 16 MB
  ushort_t* Wqk_bf = (ushort_t*)wsp;  wsp += (size_t)128 * 512 * 2;
  ushort_t* Wv_bf  = (ushort_t*)wsp;  wsp += (size_t)512 * 512 * 2;
  ushort_t* Wo_bf  = (ushort_t*)wsp;  wsp += (size_t)512 * 512 * 2;
  ushort_t* qkt    = (ushort_t*)wsp;  wsp += (size_t)16 * 1024 * 128 * 2;  // 4 MB
  ushort_t* vt2    = (ushort_t*)wsp;  wsp += (size_t)16 * 512 * 1024 * 2;  // 16 MB
  ushort_t* o1     = xbfT;  // xbfT dead after k1; reuse for o1

  prep_x    <<<dim3(16, 9, 16), 256, 0, stream>>>(x, Wq, Wk, Wv, Wo,
                                                  xbfT, Wqk_bf, Wv_bf, Wo_bf);
  k1_fused  <<<768, 256, 0, stream>>>(xbfT, Wqk_bf, Wv_bf, bq, bk, bv, qkt, vt2);
  flash_attn<<<dim3(1024), 256, 0, stream>>>(qkt, vt2, o1);
  k4_proj   <<<512, 256, 0, stream>>>(Wo_bf, o1, bo, gamma, x, out);
}

// Round 6
// 162.363 us; speedup vs baseline: 1.1464x; 1.1464x over previous
//
#include <hip/hip_runtime.h>
#include <cstddef>

// QSelfAttention MI355X round 14: TLP — 8-wave (512-thread) blocks everywhere.
// Post-mortem r13: counted-vmcnt == drain == fake-dbuf (52-53us all three);
// sync microstructure is NOT the bottleneck. All kernels run 2-3 waves/SIMD
// (Occ 19%), every pipe <25%: latency-bound with nothing to interleave.
// m114 mechanism needs >=4 waves/SIMD. This round doubles waves/CU:
//   flash: r8 geometry (c=256, no S duplication), 8 waves, 50KB LDS,
//          512 blocks -> 16 waves/CU (was 8). Plain drain barriers.
//   k1/k4: unified 128x128 tile, 8 waves (wave-tile 64x32), single-buffer
//          35KB, m97-style 2-barrier k-step. QK proj is the same tile shape.
//   swizzles + vectorized prep kept (FETCH 43->10MB proven).

typedef unsigned short ushort_t;
typedef __attribute__((ext_vector_type(8))) short bf16x8;
typedef __attribute__((ext_vector_type(4))) float f32x4;
typedef __attribute__((ext_vector_type(2))) float f32x2;
typedef __attribute__((ext_vector_type(2))) unsigned u32x2;

#define QSCALE 0.18033688011112042f  // 0.125 * log2(e)

__device__ __forceinline__ ushort_t f2bf_t(float f) {
  return (ushort_t)(__float_as_uint(f) >> 16);
}
__device__ __forceinline__ unsigned pk2bf(float lo, float hi) {
  return __builtin_amdgcn_perm(__float_as_uint(hi), __float_as_uint(lo),
                               0x07060302u);
}

__device__ __forceinline__ void gload16(const ushort_t* g, ushort_t* l) {
  __builtin_amdgcn_global_load_lds(
      (const __attribute__((address_space(1))) void*)g,
      (__attribute__((address_space(3))) void*)l, 16, 0, 0);
}

// ---------------------------------------------------------------------------
// 512-thread NT GEMM: D[128][128] = A[128x512] * B[128x512]^T, bf16, fp32 acc.
// 8 waves in 2x4 grid: wave-tile 64x32, acc[4][2] (16 MFMA / k-step / wave).
// Single-buffered LDS (As 16KB | Bs 16KB), 2 barriers per k-step.
// Per thread per step: 2 A-loads + 2 B-loads (global_load_lds w16).
__device__ __forceinline__ void gemm512(
    const ushort_t* __restrict__ A, int lda,
    const ushort_t* __restrict__ B, int ldb,
    int m0, int n0, ushort_t* As, ushort_t* Bs, f32x4 (*acc)[2])
{
  const int t = threadIdx.x;
  const int lane = t & 63, quad = lane >> 4, l15 = lane & 15;
  const int w = t >> 6, wm = w >> 2, wn4 = w & 3;
  const int rr = (lane >> 3) & 7;
  const int gg = (lane & 7) ^ rr;

  #pragma unroll
  for (int i = 0; i < 4; ++i)
    #pragma unroll
    for (int j = 0; j < 2; ++j) acc[i][j] = (f32x4){0.f, 0.f, 0.f, 0.f};

  for (int k0 = 0; k0 < 512; k0 += 64) {
    __syncthreads();  // WAR: previous step's LDS reads complete
    #pragma unroll
    for (int i = 0; i < 2; ++i) {
      const int mrow = w * 16 + i * 8;  // wave-uniform LDS base row
      gload16(A + (size_t)(m0 + mrow + rr) * lda + k0 + gg * 8, As + mrow * 64);
      gload16(B + (size_t)(n0 + mrow + rr) * ldb + k0 + gg * 8, Bs + mrow * 64);
    }
    __syncthreads();  // staged (implicit vmcnt drain at barrier)
    #pragma unroll
    for (int kk = 0; kk < 2; ++kk) {
      const int gq = kk * 4 + quad;
      const int sg = (gq ^ (l15 & 7)) * 8;
      bf16x8 af[4], bfr[2];
      #pragma unroll
      for (int i = 0; i < 4; ++i)
        af[i] = *(const bf16x8*)(As + (wm * 64 + i * 16 + l15) * 64 + sg);
      #pragma unroll
      for (int j = 0; j < 2; ++j)
        bfr[j] = *(const bf16x8*)(Bs + (wn4 * 32 + j * 16 + l15) * 64 + sg);
      #pragma unroll
      for (int i = 0; i < 4; ++i)
        #pragma unroll
        for (int j = 0; j < 2; ++j)
          acc[i][j] = __builtin_amdgcn_mfma_f32_16x16x32_bf16(
              af[i], bfr[j], acc[i][j], 0, 0, 0);
    }
  }
  __syncthreads();  // last step's reads done before LDS reuse by epilogue
}

// bf16 store epilogue for the 8-wave 128x128 tile (stride-136 LDS transpose).
template <class F>
__device__ __forceinline__ void store_bf16_512(
    ushort_t* lds, ushort_t* __restrict__ out, int ldo, int m0, int n0,
    f32x4 (*acc)[2], F f)
{
  const int t = threadIdx.x;
  const int lane = t & 63, quad = lane >> 4, l15 = lane & 15;
  const int w = t >> 6, wm = w >> 2, wn4 = w & 3;
  #pragma unroll
  for (int i = 0; i < 4; ++i)
    #pragma unroll
    for (int j = 0; j < 2; ++j)
      #pragma unroll
      for (int r = 0; r < 4; ++r) {
        const int rl = wm * 64 + i * 16 + quad * 4 + r;
        const int cl = wn4 * 32 + j * 16 + l15;
        lds[rl * 136 + cl] = f2bf_t(f(i, j, r, acc[i][j][r]));
      }
  __syncthreads();
  #pragma unroll
  for (int i = 0; i < 4; ++i) {
    const int s = i * 512 + t, m = s >> 4, g = s & 15;
    const uint4 v = *(const uint4*)(lds + m * 136 + g * 8);
    *(uint4*)(out + (size_t)(m0 + m) * ldo + n0 + g * 8) = v;
  }
}

// ---------------------------------------------------------------------------
// prep: x[b][c][n] fp32 -> xbfT[b][n][c] bf16 (64x64 tiles, blockIdx.y<8)
//       + all weight fp32->bf16 conversions (blockIdx.y==8). 256 threads.
__global__ __launch_bounds__(256) void prep_x(
    const float* __restrict__ x,
    const float* __restrict__ Wq, const float* __restrict__ Wk,
    const float* __restrict__ Wv, const float* __restrict__ Wo,
    ushort_t* __restrict__ xbfT, ushort_t* __restrict__ Wqk,
    ushort_t* __restrict__ Wvb, ushort_t* __restrict__ Wob)
{
  __shared__ float T[64 * 66];
  const int t = threadIdx.x;
  if (blockIdx.y == 8) {
    const int id = blockIdx.z * 16 + blockIdx.x;
    #pragma unroll
    for (int p = 0; p < 5; ++p) {
      const int s = p * 256 + t;
      if (s < 1152) {
        const int u = id * 1152 + s;
        const int e = u * 2;
        float f0, f1;
        if (e < 32768)       { f0 = Wq[e];         f1 = Wq[e + 1]; }
        else if (e < 65536)  { f0 = Wk[e - 32768]; f1 = Wk[e - 32767]; }
        else if (e < 327680) { f0 = Wv[e - 65536]; f1 = Wv[e - 65535]; }
        else                 { f0 = Wo[e - 327680]; f1 = Wo[e - 327679]; }
        const unsigned pk = pk2bf(f0, f1);
        if (e < 65536)       *((unsigned*)Wqk + u) = pk;
        else if (e < 327680) *((unsigned*)Wvb + (u - 32768)) = pk;
        else                 *((unsigned*)Wob + (u - 163840)) = pk;
      }
    }
    return;
  }
  const int b = blockIdx.z, c0 = blockIdx.y * 64, n0 = blockIdx.x * 64;
  const float* xb = x + ((size_t)b * 512 + c0) * 1024 + n0;
  const int njf = t & 15, ci0 = t >> 4;
  #pragma unroll
  for (int p = 0; p < 4; ++p) {
    const int ci = p * 16 + ci0;
    const f32x4 v = *(const f32x4*)(xb + (size_t)ci * 1024 + njf * 4);
    float* d = &T[ci * 66 + njf * 4];
    *(f32x2*)(d)     = (f32x2){v[0], v[1]};
    *(f32x2*)(d + 2) = (f32x2){v[2], v[3]};
  }
  __syncthreads();
  const int c4 = (t & 15) * 4, nr0 = t >> 4;
  #pragma unroll
  for (int p = 0; p < 4; ++p) {
    const int nr = p * 16 + nr0;
    const float a0 = T[(c4 + 0) * 66 + nr];
    const float a1 = T[(c4 + 1) * 66 + nr];
    const float a2 = T[(c4 + 2) * 66 + nr];
    const float a3 = T[(c4 + 3) * 66 + nr];
    const u32x2 pkv = {pk2bf(a0, a1), pk2bf(a2, a3)};
    *(u32x2*)&xbfT[((size_t)b * 1024 + n0 + nr) * 512 + c0 + c4] = pkv;
  }
}

// ---------------------------------------------------------------------------
// k1 fused (512 threads): 640 blocks = 8 XCD x 80; wid batch-contiguous.
//   r<32 : V proj   vt2[b][c][n] = Wvb . xbfT^T  (m0 c-tile, n0 n-tile)
//   r>=32: QK proj  qkt[b][n][0..127] = xbfT . Wqk^T (m0 n-tile, n0=0)
__global__ __launch_bounds__(512) void k1_fused(
    const ushort_t* __restrict__ xbfT, const ushort_t* __restrict__ Wqk,
    const ushort_t* __restrict__ Wvb,
    const float* __restrict__ bq, const float* __restrict__ bk,
    const float* __restrict__ bv,
    ushort_t* __restrict__ qkt, ushort_t* __restrict__ vt2)
{
  __shared__ __align__(16) ushort_t lds[17408];  // staging 32KB; store 34.8KB
  const unsigned lin = blockIdx.x;
  const unsigned wid = (lin & 7) * 80 + (lin >> 3);
  const int b = wid / 40, r = wid % 40;
  const int t = threadIdx.x, lane = t & 63, quad = lane >> 4, l15 = lane & 15;
  const int w = t >> 6, wm = w >> 2, wn4 = w & 3;
  f32x4 acc[4][2];
  if (r < 32) {
    const int m0 = (r >> 3) * 128, n0 = (r & 7) * 128;
    gemm512(Wvb, 512, xbfT + (size_t)b * 524288, 512, m0, n0,
            lds, lds + 8192, acc);
    float br[4][4];
    #pragma unroll
    for (int i = 0; i < 4; ++i)
      #pragma unroll
      for (int r2 = 0; r2 < 4; ++r2)
        br[i][r2] = bv[m0 + wm * 64 + i * 16 + quad * 4 + r2];
    store_bf16_512(lds, vt2 + (size_t)b * 524288, 1024, m0, n0, acc,
        [&](int i, int, int r2, float v) { return v + br[i][r2]; });
  } else {
    const int m0 = (r - 32) * 128;
    gemm512(xbfT + (size_t)b * 524288, 512, Wqk, 512, m0, 0,
            lds, lds + 8192, acc);
    float bc[2], qs[2];
    #pragma unroll
    for (int j = 0; j < 2; ++j) {
      const int col = wn4 * 32 + j * 16 + l15;
      bc[j] = (col < 64) ? bq[col] : bk[col - 64];
      qs[j] = (col < 64) ? QSCALE : 1.0f;
    }
    store_bf16_512(lds, qkt + (size_t)b * 131072, 128, m0, 0, acc,
        [&](int, int j, int, float v) { return (v + bc[j]) * qs[j]; });
  }
}

// ---------------------------------------------------------------------------
// flash (512 threads): per block (b, 64 q-rows m0, 256 c-cols c0);
// 16 chunks x 64 keys. 8 waves in 2x4 grid: S wave-tile q32xk16 (4 MFMA),
// PV wave-tile q32xc64 (16 MFMA). Single-buffer drain structure (r8-proven).
// LDS: Ks[64][64] | Vs[256][64] | Ps[64][72] = 50176 B. 512 blocks ->
// 2 blocks/CU = 16 waves/CU (4/SIMD), 2x r13.
__global__ __launch_bounds__(512) void flash_attn(
    const ushort_t* __restrict__ qkt, const ushort_t* __restrict__ vt2,
    ushort_t* __restrict__ o1)
{
  __shared__ __align__(16) ushort_t buf[25088];
  __shared__ float lsum[64][4];
  ushort_t* Ks = buf;            // 4096 ush
  ushort_t* Vs = buf + 4096;     // 16384 ush
  ushort_t* Ps = buf + 20480;    // 4608 ush (stride 72); Q-stage uses 4096

  const int t = threadIdx.x;
  const int lane = t & 63, quad = lane >> 4, l15 = lane & 15;
  const int w = t >> 6, wm = w >> 2, wn4 = w & 3;
  const int rr = (lane >> 3) & 7, gg = (lane & 7) ^ rr;

  // bijective XCD swizzle over 512 blocks: XCD k owns batches {2k,2k+1}
  const unsigned lin = blockIdx.x;
  const unsigned wid = (lin & 7) * 64 + (lin >> 3);
  const int b  = wid >> 5;
  const int m0 = ((wid >> 1) & 15) * 64;
  const int c0 = (wid & 1) * 256;

  const ushort_t* qb = qkt + (size_t)b * 131072;   // [n][128]: q 0..63, k 64..127
  const ushort_t* vb = vt2 + (size_t)b * 524288;   // [c][1024]

  // stage Q (64x64) into Ps region: 1 load/thread, wave rows w*8..w*8+7
  gload16(qb + (size_t)(m0 + w * 8 + rr) * 128 + gg * 8, Ps + (w * 8) * 64);
  __syncthreads();
  bf16x8 af_q[2][2];
  #pragma unroll
  for (int kk = 0; kk < 2; ++kk) {
    const int sg = ((kk * 4 + quad) ^ (l15 & 7)) * 8;
    #pragma unroll
    for (int i = 0; i < 2; ++i)
      af_q[i][kk] = *(const bf16x8*)(Ps + (wm * 32 + i * 16 + l15) * 64 + sg);
  }

  f32x4 accO[2][4];
  #pragma unroll
  for (int i = 0; i < 2; ++i)
    #pragma unroll
    for (int j = 0; j < 4; ++j) accO[i][j] = (f32x4){0.f, 0.f, 0.f, 0.f};
  float rsum[2][4] = {{0.f, 0.f, 0.f, 0.f}, {0.f, 0.f, 0.f, 0.f}};

  ushort_t* ps_w = Ps + (wm * 32 + quad * 4) * 72 + wn4 * 16 + l15;
  const int sg0 = (quad ^ (l15 & 7)) * 8;
  const int sg1 = ((4 + quad) ^ (l15 & 7)) * 8;

  #pragma unroll 1
  for (int mc = 0; mc < 1024; mc += 64) {
    __syncthreads();  // A: prev chunk's LDS reads (and Q-frag reads) done
    gload16(qb + (size_t)(mc + w * 8 + rr) * 128 + 64 + gg * 8,
            Ks + (w * 8) * 64);
    #pragma unroll
    for (int i = 0; i < 4; ++i)
      gload16(vb + (size_t)(c0 + w * 32 + i * 8 + rr) * 1024 + mc + gg * 8,
              Vs + (w * 32 + i * 8) * 64);
    __syncthreads();  // B: staged

    // S-phase: rows wm*32+{0,16}, keys wn4*16, K=64 (Q pre-scaled)
    f32x4 accS[2];
    accS[0] = (f32x4){0.f, 0.f, 0.f, 0.f};
    accS[1] = (f32x4){0.f, 0.f, 0.f, 0.f};
    #pragma unroll
    for (int kk = 0; kk < 2; ++kk) {
      const int sg = kk ? sg1 : sg0;
      const bf16x8 bk_ = *(const bf16x8*)(Ks + (wn4 * 16 + l15) * 64 + sg);
      #pragma unroll
      for (int i = 0; i < 2; ++i)
        accS[i] = __builtin_amdgcn_mfma_f32_16x16x32_bf16(
            af_q[i][kk], bk_, accS[i], 0, 0, 0);
    }
    // exp2 -> rsum partials -> Ps (trunc bf16); 8 values/thread
    #pragma unroll
    for (int i = 0; i < 2; ++i)
      #pragma unroll
      for (int r2 = 0; r2 < 4; ++r2) {
        const float e = __builtin_amdgcn_exp2f(accS[i][r2]);
        rsum[i][r2] += e;
        ps_w[(i * 16 + r2) * 72] = f2bf_t(e);
      }
    __syncthreads();  // C: Ps visible

    // PV-phase: O[64][256] += Ps[64][64] . Vs[256][64]^T
    #pragma unroll
    for (int kk = 0; kk < 2; ++kk) {
      const int gq = kk * 4 + quad;
      const int sgv = kk ? sg1 : sg0;
      bf16x8 ap[2], bv_[4];
      #pragma unroll
      for (int i = 0; i < 2; ++i)
        ap[i] = *(const bf16x8*)(Ps + (wm * 32 + i * 16 + l15) * 72 + gq * 8);
      #pragma unroll
      for (int j = 0; j < 4; ++j)
        bv_[j] = *(const bf16x8*)(Vs + (wn4 * 64 + j * 16 + l15) * 64 + sgv);
      #pragma unroll
      for (int i = 0; i < 2; ++i)
        #pragma unroll
        for (int j = 0; j < 4; ++j)
          accO[i][j] = __builtin_amdgcn_mfma_f32_16x16x32_bf16(
              ap[i], bv_[j], accO[i][j], 0, 0, 0);
    }
  }

  // row sums: reduce over 16 key-lanes, store per-wn4 partial
  #pragma unroll
  for (int i = 0; i < 2; ++i)
    #pragma unroll
    for (int r2 = 0; r2 < 4; ++r2) {
      float s = rsum[i][r2];
      #pragma unroll
      for (int d = 1; d < 16; d <<= 1) s += __shfl_xor(s, d, 16);
      if (l15 == 0) lsum[wm * 32 + i * 16 + quad * 4 + r2][wn4] = s;
    }
  __syncthreads();  // last PV reads done; lsum visible

  ushort_t* fl_b = buf;  // [64][264] = 16896 ush (Ks/Vs dead; Ps untouched)
  #pragma unroll
  for (int i = 0; i < 2; ++i)
    #pragma unroll
    for (int r2 = 0; r2 < 4; ++r2) {
      const int row = wm * 32 + i * 16 + quad * 4 + r2;
      const float inv = 1.0f / (lsum[row][0] + lsum[row][1] +
                                lsum[row][2] + lsum[row][3]);
      #pragma unroll
      for (int j = 0; j < 4; ++j)
        fl_b[row * 264 + wn4 * 64 + j * 16 + l15] = f2bf_t(accO[i][j][r2] * inv);
    }
  __syncthreads();
  #pragma unroll
  for (int pp = 0; pp < 2; ++pp) {
    const int s = pp * 512 + t, m = s >> 4, g = s & 15;
    const uint4 v = *(const uint4*)(fl_b + m * 264 + g * 8);
    *(uint4*)(o1 + ((size_t)b * 1024 + m0 + m) * 512 + c0 + g * 8) = v;
  }
}

// ---------------------------------------------------------------------------
// K4 (512 threads): out[b][c][n] = g*(Wo @ o1^T + bo) + x. Exact fp32 path.
__global__ __launch_bounds__(512) void k4_proj(
    const ushort_t* __restrict__ Wob, const ushort_t* __restrict__ o1,
    const float* __restrict__ bo, const float* __restrict__ gamma,
    const float* __restrict__ x, float* __restrict__ out)
{
  __shared__ __align__(16) ushort_t lds[17408];  // staging 32KB; fl 33.8KB
  const unsigned lin = blockIdx.x;
  const unsigned wid = (lin & 7) * 64 + (lin >> 3);
  const int b = wid >> 5, rem = wid & 31;
  const int m0 = (rem >> 3) * 128, n0 = (rem & 7) * 128;
  f32x4 acc[4][2];
  gemm512(Wob, 512, o1 + (size_t)b * 524288, 512, m0, n0,
          lds, lds + 8192, acc);
  const int t = threadIdx.x, lane = t & 63, quad = lane >> 4, l15 = lane & 15;
  const int w = t >> 6, wm = w >> 2, wn4 = w & 3;
  const float g = gamma[0];
  float br[4][4];
  #pragma unroll
  for (int i = 0; i < 4; ++i)
    #pragma unroll
    for (int r2 = 0; r2 < 4; ++r2)
      br[i][r2] = bo[m0 + wm * 64 + i * 16 + quad * 4 + r2];
  float* fl = (float*)lds;  // 64 rows x 132 f stride (33792 B)
  #pragma unroll
  for (int h = 0; h < 2; ++h) {
    if (wm == h) {
      #pragma unroll
      for (int i = 0; i < 4; ++i)
        #pragma unroll
        for (int j = 0; j < 2; ++j)
          #pragma unroll
          for (int r2 = 0; r2 < 4; ++r2)
            fl[(i * 16 + quad * 4 + r2) * 132 + wn4 * 32 + j * 16 + l15] =
                g * (acc[i][j][r2] + br[i][r2]);
    }
    __syncthreads();
    #pragma unroll
    for (int i2 = 0; i2 < 4; ++i2) {
      const int s = i2 * 512 + t, m = s >> 5, c4 = s & 31;
      f32x4 v = *(const f32x4*)(fl + m * 132 + c4 * 4);
      const size_t gi = ((size_t)b * 512 + m0 + h * 64 + m) * 1024 + n0 + c4 * 4;
      const f32x4 xr = *(const f32x4*)(x + gi);
      v += xr;
      *(f32x4*)(out + gi) = v;
    }
    __syncthreads();
  }
}

// ---------------------------------------------------------------------------
extern "C" void kernel_launch(void* const* d_in, const int* in_sizes, int n_in,
                              void* d_out, int out_size, void* d_ws, size_t ws_size,
                              hipStream_t stream) {
  const float* x     = (const float*)d_in[0];
  const float* Wq    = (const float*)d_in[1];
  const float* bq    = (const float*)d_in[2];
  const float* Wk    = (const float*)d_in[3];
  const float* bk    = (const float*)d_in[4];
  const float* Wv    = (const float*)d_in[5];
  const float* bv    = (const float*)d_in[6];
  const float* Wo    = (const float*)d_in[7];
  const float* bo    = (const float*)d_in[8];
  const float* gamma = (const float*)d_in[9];
  float* out = (float*)d_out;

  char* wsp = (char*)d_ws;
  ushort_t* xbfT   = (ushort_t*)wsp;  wsp += (size_t)16 * 1024 * 512 * 2;  // 16 MB
  ushort_t* Wqk_bf = (ushort_t*)wsp;  wsp += (size_t)128 * 512 * 2;
  ushort_t* Wv_bf  = (ushort_t*)wsp;  wsp += (size_t)512 * 512 * 2;
  ushort_t* Wo_bf  = (ushort_t*)wsp;  wsp += (size_t)512 * 512 * 2;
  ushort_t* qkt    = (ushort_t*)wsp;  wsp += (size_t)16 * 1024 * 128 * 2;  // 4 MB
  ushort_t* vt2    = (ushort_t*)wsp;  wsp += (size_t)16 * 512 * 1024 * 2;  // 16 MB
  ushort_t* o1     = xbfT;  // xbfT dead after k1; reuse for o1

  prep_x    <<<dim3(16, 9, 16), 256, 0, stream>>>(x, Wq, Wk, Wv, Wo,
                                                  xbfT, Wqk_bf, Wv_bf, Wo_bf);
  k1_fused  <<<640, 512, 0, stream>>>(xbfT, Wqk_bf, Wv_bf, bq, bk, bv, qkt, vt2);
  flash_attn<<<512, 512, 0, stream>>>(qkt, vt2, o1);
  k4_proj   <<<512, 512, 0, stream>>>(Wo_bf, o1, bo, gamma, x, out);
}